// Round 14
// baseline (394.136 us; speedup 1.0000x reference)
//
#include <hip/hip_runtime.h>
#include <math.h>

#define HIDDEN 4096
#define QKV_N 6144      // (32 + 2*8) * 128
#define T_LEN 2048
#define HD 128
#define N_HEADS 32
#define N_KV 8
#define SCALE 0.08838834764831845f  // 128^-0.5

typedef unsigned short u16;
typedef unsigned int u32;
typedef __attribute__((ext_vector_type(8))) short bf16x8;
typedef __attribute__((ext_vector_type(4))) float f32x4;

// fp32 -> bf16 round-to-nearest-even
__device__ __forceinline__ u16 f2b(float x) {
  u32 u = __builtin_bit_cast(u32, x);
  u += 0x7fffu + ((u >> 16) & 1u);
  return (u16)(u >> 16);
}

typedef const __attribute__((address_space(1))) void* gas_ptr;
typedef __attribute__((address_space(3))) void* las_ptr;
__device__ __forceinline__ void gll16(const void* g, void* l) {
  __builtin_amdgcn_global_load_lds((gas_ptr)g, (las_ptr)l, 16, 0, 0);
}

// ---------------------------------------------------------------------------
// elementwise fp32 -> bf16 cast (4 elems/thread)
// ---------------------------------------------------------------------------
__global__ __launch_bounds__(256) void cast_bf16_kernel(
    const float* __restrict__ in, u16* __restrict__ out) {
  const size_t i = ((size_t)blockIdx.x * 256 + threadIdx.x) * 4;
  f32x4 v = *(const f32x4*)(in + i);
  ushort4 o;
  o.x = f2b(v[0]); o.y = f2b(v[1]); o.z = f2b(v[2]); o.w = f2b(v[3]);
  *(ushort4*)(out + i) = o;
}

// ---------------------------------------------------------------------------
// W [K][N] fp32 -> WT [N][K] bf16 (32x32 LDS tile transpose)
// ---------------------------------------------------------------------------
__global__ __launch_bounds__(256) void transpose_cast_kernel(
    const float* __restrict__ W, u16* __restrict__ WT, int K, int N) {
  __shared__ float t[32][33];
  const int n0 = blockIdx.x * 32, k0 = blockIdx.y * 32;
  const int c = threadIdx.x & 31;
  const int r0 = threadIdx.x >> 5;
#pragma unroll
  for (int j = 0; j < 4; ++j) {
    const int r = r0 + 8 * j;
    t[c][r] = W[(size_t)(k0 + r) * N + n0 + c];
  }
  __syncthreads();
#pragma unroll
  for (int j = 0; j < 4; ++j) {
    const int n = r0 + 8 * j;
    WT[(size_t)(n0 + n) * K + k0 + c] = f2b(t[n][c]);
  }
}

// ---------------------------------------------------------------------------
// 8-phase BMxBN bf16 MFMA GEMM (r7 schedule — best measured of 7 variants).
// BK=64, 512 thr (8 waves 2Mx4N; per-wave C = BM/2 x BN/4).
// vmcnt ledger: waits leave exactly the next tile's first 2 units in flight
// -> vmcnt(ALOADS+BLOADS). Octet swizzle o ^= (r>>1)&3 on stage-source AND
// ds_read (involution) -> 0 bank conflicts. No XCD swizzle (r11 regression).
// ---------------------------------------------------------------------------
template <int BM, int BN>
__global__ __launch_bounds__(512, 2) void gemm256_kernel(
    const u16* __restrict__ A, const u16* __restrict__ BT,
    float* __restrict__ C, int M, int N, int K) {
  constexpr int WCOLS = BN / 4;
  constexpr int NF = WCOLS / 16;
  constexpr int NF2 = NF / 2;
  constexpr int MF = BM / 32;
  constexpr int ALOADS = BM / 128;
  constexpr int BLOADS = BN / 128;
  constexpr int VMN = ALOADS + BLOADS;
  __shared__ __align__(16) u16 As[2][2][BM * 32];
  __shared__ __align__(16) u16 Bs[2][2][BN * 32];

  const int tid = threadIdx.x;
  const int w = tid >> 6, l = tid & 63;
  const int wr = w >> 2, wc = w & 3;
  const int m = l & 15, g = l >> 4;
  const int bm = blockIdx.y * BM, bn = blockIdx.x * BN;
  const int NT = K >> 6;

  size_t gA[2]; int sA[2];
  size_t gB[2]; int sB[2];
#pragma unroll
  for (int i = 0; i < ALOADS; ++i) {
    const int s = i * 512 + tid;
    const int r = s >> 2, o = s & 3;
    sA[i] = s * 8;
    gA[i] = (size_t)(bm + r) * K + (o ^ ((r >> 1) & 3)) * 8;
  }
#pragma unroll
  for (int i = 0; i < BLOADS; ++i) {
    const int s = i * 512 + tid;
    const int r = s >> 2, o = s & 3;
    sB[i] = s * 8;
    gB[i] = (size_t)(bn + r) * K + (o ^ ((r >> 1) & 3)) * 8;
  }

  const int foff = m * 32 + ((g ^ ((m >> 1) & 3)) * 8);
  const int abase = wr * (BM / 2) * 32;
  const int bbase = wc * WCOLS * 32;

#define STAGE_A(tile, kh)                                                      \
  {                                                                            \
    const size_t kofs = (size_t)(tile) * 64 + (kh) * 32;                       \
    u16* dst = &As[(tile) & 1][kh][0];                                         \
    gll16(A + gA[0] + kofs, dst + sA[0]);                                      \
    if constexpr (ALOADS > 1) gll16(A + gA[1] + kofs, dst + sA[1]);            \
  }
#define STAGE_B(tile, kh)                                                      \
  {                                                                            \
    const size_t kofs = (size_t)(tile) * 64 + (kh) * 32;                       \
    u16* dst = &Bs[(tile) & 1][kh][0];                                         \
    gll16(BT + gB[0] + kofs, dst + sB[0]);                                     \
    if constexpr (BLOADS > 1) gll16(BT + gB[1] + kofs, dst + sB[1]);           \
  }
#define VM_COUNTED()                                                           \
  {                                                                            \
    if constexpr (VMN == 4)                                                    \
      asm volatile("s_waitcnt vmcnt(4)" ::: "memory");                         \
    else                                                                       \
      asm volatile("s_waitcnt vmcnt(3)" ::: "memory");                         \
  }
#define PHASE(j, b, DO_STAGE, tn, VM)                                          \
  {                                                                            \
    constexpr int qn = (j) & 1, kh = (j) >> 1;                                 \
    if constexpr (qn == 0) {                                                   \
      _Pragma("unroll") for (int fm = 0; fm < MF; ++fm)                        \
          af[fm] = *(const bf16x8*)(&As[b][kh][abase + fm * 512 + foff]);      \
    }                                                                          \
    bf16x8 bf[NF2];                                                            \
    _Pragma("unroll") for (int fn = 0; fn < NF2; ++fn)                         \
        bf[fn] =                                                               \
        *(const bf16x8*)(&Bs[b][kh][bbase + (qn * NF2 + fn) * 512 + foff]);    \
    if constexpr (DO_STAGE) {                                                  \
      if constexpr ((j) == 0) STAGE_A(tn, 0);                                  \
      if constexpr ((j) == 1) STAGE_B(tn, 0);                                  \
      if constexpr ((j) == 2) STAGE_A(tn, 1);                                  \
      if constexpr ((j) == 3) STAGE_B(tn, 1);                                  \
    }                                                                          \
    asm volatile("" ::: "memory");                                             \
    __builtin_amdgcn_s_barrier();                                              \
    asm volatile("" ::: "memory");                                             \
    __builtin_amdgcn_s_setprio(1);                                             \
    _Pragma("unroll") for (int fm = 0; fm < MF; ++fm)                          \
        _Pragma("unroll") for (int fn = 0; fn < NF2; ++fn)                     \
        acc[fm][qn * NF2 + fn] = __builtin_amdgcn_mfma_f32_16x16x32_bf16(      \
            af[fm], bf[fn], acc[fm][qn * NF2 + fn], 0, 0, 0);                  \
    __builtin_amdgcn_s_setprio(0);                                             \
    asm volatile("" ::: "memory");                                             \
    if constexpr (((j) & 1) && (VM) == 0)                                      \
      asm volatile("s_waitcnt vmcnt(0)" ::: "memory");                         \
    if constexpr (((j) & 1) && (VM) == 1) VM_COUNTED();                        \
    __builtin_amdgcn_s_barrier();                                              \
    asm volatile("" ::: "memory");                                             \
  }

  f32x4 acc[MF][NF];
#pragma unroll
  for (int i = 0; i < MF; ++i)
#pragma unroll
    for (int j = 0; j < NF; ++j) acc[i][j] = (f32x4){0.f, 0.f, 0.f, 0.f};

  STAGE_A(0, 0); STAGE_B(0, 0); STAGE_A(0, 1); STAGE_B(0, 1);
  VM_COUNTED();
  __builtin_amdgcn_s_barrier();
  asm volatile("" ::: "memory");

  bf16x8 af[MF];
  for (int t = 0; t < NT - 1; ++t) {
    const int b = t & 1, tn = t + 1;
    PHASE(0, b, true, tn, 1);
    PHASE(1, b, true, tn, 1);
    PHASE(2, b, true, tn, 1);
    PHASE(3, b, true, tn, 1);
  }
  {
    const int b = (NT - 1) & 1;
    PHASE(0, b, false, 0, 2);
    PHASE(1, b, false, 0, 0);
    PHASE(2, b, false, 0, 2);
    PHASE(3, b, false, 0, 2);
  }
#undef PHASE
#undef VM_COUNTED
#undef STAGE_B
#undef STAGE_A

#pragma unroll
  for (int fm = 0; fm < MF; ++fm) {
    const int row = bm + wr * (BM / 2) + fm * 16 + g * 4;
#pragma unroll
    for (int fn = 0; fn < NF; ++fn) {
      const int col = bn + wc * WCOLS + fn * 16 + m;
      float* cp = C + (size_t)row * N + col;
#pragma unroll
      for (int r = 0; r < 4; ++r) cp[(size_t)r * N] = acc[fm][fn][r];
    }
  }
}

// ---------------------------------------------------------------------------
// Fused per-head RMSNorm + partial RoPE -> packed bf16.
// ---------------------------------------------------------------------------
__global__ __launch_bounds__(128) void normrope_pack_kernel(
    const float* __restrict__ qkv, const int* __restrict__ positions,
    const float* __restrict__ qw, const float* __restrict__ kw,
    u16* __restrict__ Qp, u16* __restrict__ Kp) {
  const int t = blockIdx.x;
  const int hh = blockIdx.y;  // 0..39
  const int d = threadIdx.x;  // 0..127
  const bool isq = hh < N_HEADS;
  const int col = isq ? hh * HD : HIDDEN + (hh - N_HEADS) * HD;
  const float* row = qkv + (size_t)t * QKV_N + col;
  const float* w = isq ? qw : kw;

  float x = row[d];
  float ss = x * x;
#pragma unroll
  for (int off = 32; off >= 1; off >>= 1) ss += __shfl_xor(ss, off);
  __shared__ float wsum[2];
  __shared__ float xs[128];
  if ((d & 63) == 0) wsum[d >> 6] = ss;
  __syncthreads();
  const float tot = wsum[0] + wsum[1];
  const float inv = rsqrtf(tot * (1.f / 128.f) + 1e-6f);
  const float xn = x * inv * w[d];
  xs[d] = xn;
  __syncthreads();

  float outv;
  if (d < 64) {
    const int idx = d & 31;
    const float invf = powf(1.0e6f, -(float)idx * (1.0f / 32.0f));
    const float fr = (float)positions[t] * invf;
    const float c = cosf(fr), s = sinf(fr);
    const float x1 = xs[idx], x2 = xs[idx + 32];
    outv = (d < 32) ? (x1 * c - x2 * s) : (x2 * c + x1 * s);
  } else {
    outv = xn;
  }
  if (isq) {
    Qp[((size_t)hh * T_LEN + t) * HD + d] = f2b(outv * SCALE);
  } else {
    Kp[((size_t)(hh - N_HEADS) * T_LEN + t) * HD + d] = f2b(outv);
  }
}

// ---------------------------------------------------------------------------
// V transpose+cast: qkv V region fp32 [t][d] -> Vtp[kvh][d][t] bf16.
// ---------------------------------------------------------------------------
__global__ __launch_bounds__(256) void vtrans_kernel(
    const float* __restrict__ qkv, u16* __restrict__ Vtp) {
  __shared__ float tile[32][132];
  const int t0 = blockIdx.x * 32;
  const int kvh = blockIdx.y;
  const int tv = threadIdx.x >> 3;          // 0..31
  const int c0 = (threadIdx.x & 7) * 16;    // 0..112
  const float* src =
      qkv + (size_t)(t0 + tv) * QKV_N + (HIDDEN + 1024) + kvh * HD + c0;
#pragma unroll
  for (int u = 0; u < 4; ++u)
    *(f32x4*)&tile[tv][c0 + 4 * u] = *(const f32x4*)(src + 4 * u);
  __syncthreads();
  const int dd = threadIdx.x >> 1;   // 0..127
  const int half = threadIdx.x & 1;  // 0,1
  u16 buf[16];
#pragma unroll
  for (int p = 0; p < 16; ++p) buf[p] = f2b(tile[half * 16 + p][dd]);
  u16* dst = Vtp + ((size_t)kvh * HD + dd) * T_LEN + t0 + half * 16;
  *(uint4*)dst = *(uint4*)&buf[0];
  *(uint4*)(dst + 8) = *(uint4*)&buf[8];
}

// ---------------------------------------------------------------------------
// MFMA causal GQA flash attention v5: 128-row Q-tiles, 2 q-sets per wave
// sharing one K/V fragment register load (halves LDS reads per FLOP —
// K/V-frag traffic is independent of q-rows since Q is register-hoisted).
// grid (8, 32): block bx does Q-tiles qb = 15-bx then bx (NT sum = 68
// const -> no tail). 256 thr (4 waves), LDS 72KB. Defer-max + setprio.
// Set0 (rows t0..t0+63) skipped (wave-uniform) for tiles past its diagonal.
// ---------------------------------------------------------------------------
__global__ __launch_bounds__(256, 2) void attn5_kernel(
    const u16* __restrict__ Qp, const u16* __restrict__ Kp,
    const u16* __restrict__ Vtp, u16* __restrict__ outB) {
  __shared__ __align__(16) u16 Qs[128 * 128];
  __shared__ __align__(16) u16 Ks[2 * 32 * 128];
  __shared__ __align__(16) u16 Vts[2 * 128 * 32];
  __shared__ __align__(16) u16 Plds[2 * 4 * 16 * 32];

  const int bx = blockIdx.x;  // 0..7
  const int h = blockIdx.y;
  const int kvh = h >> 2;
  const int tid = threadIdx.x;
  const int w = tid >> 6, l = tid & 63;
  const int g = l >> 4, m = l & 15;

  const u16* kbase = Kp + (size_t)kvh * T_LEN * HD;
  const u16* vbase = Vtp + (size_t)kvh * HD * T_LEN;
  u16* pl0 = Plds + w * 512;         // set0 P bounce
  u16* pl1 = Plds + 2048 + w * 512;  // set1 P bounce

#define STAGE_KV(jt, b)                                                        \
  {                                                                            \
    _Pragma("unroll") for (int p = 0; p < 2; ++p) {                            \
      const int krow = p * 16 + w * 4 + (l >> 4);                              \
      const int kg = (l & 15) ^ (krow & 7);                                    \
      gll16(kbase + (size_t)((jt) * 32 + krow) * 128 + kg * 8,                 \
            Ks + (b) * 4096 + p * 2048 + w * 512 + l * 8);                     \
      const int dv = p * 64 + w * 16 + (l >> 2);                               \
      const int vg = (l & 3) ^ ((dv >> 1) & 3);                                \
      gll16(vbase + (size_t)dv * T_LEN + (jt) * 32 + vg * 8,                   \
            Vts + (b) * 4096 + p * 2048 + w * 512 + l * 8);                    \
    }                                                                          \
  }
// bounce P (s -> pl) and read back the A-fragment
#define P_BOUNCE(sv, pl, pa)                                                   \
  {                                                                            \
    const u32 a0 = (u32)f2b(sv[0][0]) | ((u32)f2b(sv[0][1]) << 16);            \
    const u32 a1 = (u32)f2b(sv[0][2]) | ((u32)f2b(sv[0][3]) << 16);            \
    const u32 b0 = (u32)f2b(sv[1][0]) | ((u32)f2b(sv[1][1]) << 16);            \
    const u32 b1 = (u32)f2b(sv[1][2]) | ((u32)f2b(sv[1][3]) << 16);            \
    *(uint2*)((pl) + m * 32 + ((g ^ (m >> 1)) * 4)) = make_uint2(a0, a1);      \
    *(uint2*)((pl) + m * 32 + (((g + 4) ^ (m >> 1)) * 4)) = make_uint2(b0, b1);\
    const uint2 lo = *(const uint2*)((pl) + m * 32 + (((2 * g) ^ (m >> 1)) * 4)); \
    const uint2 hi =                                                           \
        *(const uint2*)((pl) + m * 32 + (((2 * g + 1) ^ (m >> 1)) * 4));       \
    union { u32 u[4]; bf16x8 v; } pu;                                          \
    pu.u[0] = lo.x; pu.u[1] = lo.y; pu.u[2] = hi.x; pu.u[3] = hi.y;            \
    pa = pu.v;                                                                 \
  }
// online softmax with defer-max for one set (s, mrun, lrun, o[]) -> ps added
#define SOFTMAX_SET(sv, mrun, lrun, ov)                                        \
  {                                                                            \
    float pm = fmaxf(fmaxf(fmaxf(sv[0][0], sv[0][1]), fmaxf(sv[0][2], sv[0][3])), \
                     fmaxf(fmaxf(sv[1][0], sv[1][1]), fmaxf(sv[1][2], sv[1][3]))); \
    pm = fmaxf(pm, __shfl_xor(pm, 16));                                        \
    pm = fmaxf(pm, __shfl_xor(pm, 32));                                        \
    if (!__all(pm <= mrun + 8.f)) {                                            \
      const float mn = fmaxf(mrun, pm);                                        \
      const float sc = __expf(mrun - mn);                                      \
      mrun = mn;                                                               \
      lrun *= sc;                                                              \
      f32x4 scr;                                                               \
      _Pragma("unroll") for (int r = 0; r < 4; ++r) scr[r] =                   \
          __shfl(sc, g * 4 + r);                                               \
      _Pragma("unroll") for (int n = 0; n < 8; ++n) ov[n] *= scr;              \
    }                                                                          \
    float ps = 0.f;                                                            \
    _Pragma("unroll") for (int f = 0; f < 2; ++f)                              \
        _Pragma("unroll") for (int r = 0; r < 4; ++r) {                        \
      sv[f][r] = __expf(sv[f][r] - mrun);                                      \
      ps += sv[f][r];                                                          \
    }                                                                          \
    ps += __shfl_xor(ps, 16);                                                  \
    ps += __shfl_xor(ps, 32);                                                  \
    lrun += ps;                                                                \
  }

  for (int job = 0; job < 2; ++job) {
    const int qb = job ? bx : 15 - bx;  // big first
    const int t0 = qb * 128;
    const int NT = 4 * (qb + 1);

    // ---- stage Q tile: 128 rows (swizzle: 16B granule ^ (row&7)) ----
    {
      const u16* qbase = Qp + ((size_t)h * T_LEN + t0) * HD;
#pragma unroll
      for (int p = 0; p < 8; ++p) {
        const int row = p * 16 + w * 4 + (l >> 4);
        const int gr = (l & 15) ^ (row & 7);
        gll16(qbase + row * 128 + gr * 8, Qs + p * 2048 + w * 512 + l * 8);
      }
    }
    STAGE_KV(0, 0);
    __syncthreads();

    // ---- hoist Q B-fragments for both sets ----
    bf16x8 qf0[4], qf1[4];
    {
      const u16* qr0 = Qs + (w * 16 + m) * 128;
      const u16* qr1 = Qs + (64 + w * 16 + m) * 128;
#pragma unroll
      for (int kk = 0; kk < 4; ++kk) {
        const int go = ((kk * 4 + g) ^ (m & 7)) * 8;
        qf0[kk] = *(const bf16x8*)(qr0 + go);
        qf1[kk] = *(const bf16x8*)(qr1 + go);
      }
    }

    f32x4 o0[8], o1[8];
#pragma unroll
    for (int n = 0; n < 8; ++n) {
      o0[n] = (f32x4){0.f, 0.f, 0.f, 0.f};
      o1[n] = (f32x4){0.f, 0.f, 0.f, 0.f};
    }
    float mrun0 = -1e30f, lrun0 = 0.f, mrun1 = -1e30f, lrun1 = 0.f;
    const int qg0 = t0 + w * 16 + m;
    const int qg1 = t0 + 64 + w * 16 + m;

    for (int jt = 0; jt < NT; ++jt) {
      const int b = jt & 1;
      if (jt + 1 < NT) STAGE_KV(jt + 1, b ^ 1);
      const bool do0 = (jt * 32 <= t0 + 63);  // tile intersects set0's range

      // ---- K fragments once, reused by both q-sets ----
      bf16x8 kfr[8];
#pragma unroll
      for (int f = 0; f < 2; ++f)
#pragma unroll
        for (int kk = 0; kk < 4; ++kk)
          kfr[f * 4 + kk] = *(const bf16x8*)(
              Ks + b * 4096 + (f * 16 + m) * 128 + (((kk * 4 + g) ^ (m & 7)) * 8));

      // ---- S^T = K @ Q^T for both sets ----
      f32x4 s1[2];
      s1[0] = (f32x4){0.f, 0.f, 0.f, 0.f};
      s1[1] = (f32x4){0.f, 0.f, 0.f, 0.f};
      f32x4 s0[2];
      __builtin_amdgcn_s_setprio(1);
#pragma unroll
      for (int f = 0; f < 2; ++f)
#pragma unroll
        for (int kk = 0; kk < 4; ++kk)
          s1[f] = __builtin_amdgcn_mfma_f32_16x16x32_bf16(kfr[f * 4 + kk],
                                                          qf1[kk], s1[f], 0, 0, 0);
      if (do0) {
        s0[0] = (f32x4){0.f, 0.f, 0.f, 0.f};
        s0[1] = (f32x4){0.f, 0.f, 0.f, 0.f};
#pragma unroll
        for (int f = 0; f < 2; ++f)
#pragma unroll
          for (int kk = 0; kk < 4; ++kk)
            s0[f] = __builtin_amdgcn_mfma_f32_16x16x32_bf16(
                kfr[f * 4 + kk], qf0[kk], s0[f], 0, 0, 0);
      }
      __builtin_amdgcn_s_setprio(0);

      // ---- causal masks ----
      if (jt >= NT - 2) {
        const int kvb = jt * 32 + g * 4;
#pragma unroll
        for (int f = 0; f < 2; ++f)
#pragma unroll
          for (int r = 0; r < 4; ++r)
            if (kvb + f * 16 + r > qg1) s1[f][r] = -1e30f;
      }
      if (do0 && jt >= NT - 4) {
        const int kvb = jt * 32 + g * 4;
#pragma unroll
        for (int f = 0; f < 2; ++f)
#pragma unroll
          for (int r = 0; r < 4; ++r)
            if (kvb + f * 16 + r > qg0) s0[f][r] = -1e30f;
      }

      // ---- softmax + P relayout ----
      bf16x8 pa0, pa1;
      SOFTMAX_SET(s1, mrun1, lrun1, o1);
      P_BOUNCE(s1, pl1, pa1);
      if (do0) {
        SOFTMAX_SET(s0, mrun0, lrun0, o0);
        P_BOUNCE(s0, pl0, pa0);
      }

      // ---- PV: shared V fragment, two accumulations ----
      __builtin_amdgcn_s_setprio(1);
#pragma unroll
      for (int n = 0; n < 8; ++n) {
        const int dd = n * 16 + m;
        bf16x8 vf = *(const bf16x8*)(Vts + b * 4096 + dd * 32 +
                                     ((g ^ ((dd >> 1) & 3)) * 8));
        o1[n] = __builtin_amdgcn_mfma_f32_16x16x32_bf16(pa1, vf, o1[n], 0, 0, 0);
        if (do0)
          o0[n] = __builtin_amdgcn_mfma_f32_16x16x32_bf16(pa0, vf, o0[n], 0, 0, 0);
      }
      __builtin_amdgcn_s_setprio(0);
      __syncthreads();
    }

    // ---- epilogue: normalize rows, write bf16 [t][h*128+d], both sets ----
    float li0[4], li1[4];
#pragma unroll
    for (int r = 0; r < 4; ++r) {
      li0[r] = 1.f / __shfl(lrun0, g * 4 + r);
      li1[r] = 1.f / __shfl(lrun1, g * 4 + r);
    }
    u16* ob0 = outB + (size_t)(t0 + w * 16 + g * 4) * HIDDEN + h * HD + m;
    u16* ob1 = ob0 + (size_t)64 * HIDDEN;
#pragma unroll
    for (int n = 0; n < 8; ++n)
#pragma unroll
      for (int r = 0; r < 4; ++r) {
        ob0[(size_t)r * HIDDEN + n * 16] = f2b(o0[n][r] * li0[r]);
        ob1[(size_t)r * HIDDEN + n * 16] = f2b(o1[n][r] * li1[r]);
      }
  }
#undef SOFTMAX_SET
#undef P_BOUNCE
#undef STAGE_KV
}

// ---------------------------------------------------------------------------
extern "C" void kernel_launch(void* const* d_in, const int* in_sizes, int n_in,
                              void* d_out, int out_size, void* d_ws,
                              size_t ws_size, hipStream_t stream) {
  const float* hidden = (const float*)d_in[0];
  const int* positions = (const int*)d_in[1];
  const float* w_qkv = (const float*)d_in[2];
  const float* w_o = (const float*)d_in[3];
  const float* q_norm_w = (const float*)d_in[4];
  const float* k_norm_w = (const float*)d_in[5];
  float* out = (float*)d_out;

  // workspace layout (~176 MB); Qp aliases hiddenB (dead after GEMM1)
  u16* hiddenB = (u16*)d_ws;                                // 16.8 MB
  u16* Qp = hiddenB;                                        // alias
  u16* wqkvT = hiddenB + (size_t)T_LEN * HIDDEN;            // 50.3 MB
  u16* woT = wqkvT + (size_t)QKV_N * HIDDEN;                // 33.6 MB
  float* qkv = (float*)(woT + (size_t)HIDDEN * HIDDEN);     // 50.3 MB
  u16* attnB = (u16*)(qkv + (size_t)T_LEN * QKV_N);         // 16.8 MB
  u16* Kp = attnB + (size_t)T_LEN * HIDDEN;                 // 4.2 MB
  u16* Vtp = Kp + (size_t)N_KV * T_LEN * HD;                // 4.2 MB

  // prep
  cast_bf16_kernel<<<(T_LEN * HIDDEN) / 1024, 256, 0, stream>>>(hidden, hiddenB);
  transpose_cast_kernel<<<dim3(QKV_N / 32, HIDDEN / 32), 256, 0, stream>>>(
      w_qkv, wqkvT, HIDDEN, QKV_N);
  transpose_cast_kernel<<<dim3(HIDDEN / 32, HIDDEN / 32), 256, 0, stream>>>(
      w_o, woT, HIDDEN, HIDDEN);

  // 1) qkv = hidden @ w_qkv  (8-phase 256x256, grid 24x8 = 192)
  gemm256_kernel<256, 256><<<dim3(QKV_N / 256, T_LEN / 256), 512, 0, stream>>>(
      hiddenB, wqkvT, qkv, T_LEN, QKV_N, HIDDEN);
  // 2) RMSNorm + RoPE -> packed bf16 Q/K; V transpose -> Vtp
  normrope_pack_kernel<<<dim3(T_LEN, N_HEADS + N_KV), 128, 0, stream>>>(
      qkv, positions, q_norm_w, k_norm_w, Qp, Kp);
  vtrans_kernel<<<dim3(T_LEN / 32, N_KV), 256, 0, stream>>>(qkv, Vtp);
  // 3) MFMA causal GQA flash attention v5 (2 q-sets/wave) -> bf16
  attn5_kernel<<<dim3(8, N_HEADS), 256, 0, stream>>>(Qp, Kp, Vtp, attnB);
  // 4) out = attn @ w_o  (8-phase 128x256, grid 16x16 = 256 = full coverage)
  gemm256_kernel<128, 256><<<dim3(HIDDEN / 256, T_LEN / 128), 512, 0, stream>>>(
      attnB, woT, out, T_LEN, HIDDEN, HIDDEN);
}

// Round 15
// 358.543 us; speedup vs baseline: 1.0993x; 1.0993x over previous
//
#include <hip/hip_runtime.h>
#include <math.h>

#define HIDDEN 4096
#define QKV_N 6144      // (32 + 2*8) * 128
#define T_LEN 2048
#define HD 128
#define N_HEADS 32
#define N_KV 8
#define SCALE 0.08838834764831845f  // 128^-0.5

typedef unsigned short u16;
typedef unsigned int u32;
typedef __attribute__((ext_vector_type(8))) short bf16x8;
typedef __attribute__((ext_vector_type(4))) float f32x4;

// fp32 -> bf16 round-to-nearest-even
__device__ __forceinline__ u16 f2b(float x) {
  u32 u = __builtin_bit_cast(u32, x);
  u += 0x7fffu + ((u >> 16) & 1u);
  return (u16)(u >> 16);
}

typedef const __attribute__((address_space(1))) void* gas_ptr;
typedef __attribute__((address_space(3))) void* las_ptr;
__device__ __forceinline__ void gll16(const void* g, void* l) {
  __builtin_amdgcn_global_load_lds((gas_ptr)g, (las_ptr)l, 16, 0, 0);
}

// ---------------------------------------------------------------------------
// elementwise fp32 -> bf16 cast (4 elems/thread)
// ---------------------------------------------------------------------------
__global__ __launch_bounds__(256) void cast_bf16_kernel(
    const float* __restrict__ in, u16* __restrict__ out) {
  const size_t i = ((size_t)blockIdx.x * 256 + threadIdx.x) * 4;
  f32x4 v = *(const f32x4*)(in + i);
  ushort4 o;
  o.x = f2b(v[0]); o.y = f2b(v[1]); o.z = f2b(v[2]); o.w = f2b(v[3]);
  *(ushort4*)(out + i) = o;
}

// ---------------------------------------------------------------------------
// W [K][N] fp32 -> WT [N][K] bf16 (32x32 LDS tile transpose)
// ---------------------------------------------------------------------------
__global__ __launch_bounds__(256) void transpose_cast_kernel(
    const float* __restrict__ W, u16* __restrict__ WT, int K, int N) {
  __shared__ float t[32][33];
  const int n0 = blockIdx.x * 32, k0 = blockIdx.y * 32;
  const int c = threadIdx.x & 31;
  const int r0 = threadIdx.x >> 5;
#pragma unroll
  for (int j = 0; j < 4; ++j) {
    const int r = r0 + 8 * j;
    t[c][r] = W[(size_t)(k0 + r) * N + n0 + c];
  }
  __syncthreads();
#pragma unroll
  for (int j = 0; j < 4; ++j) {
    const int n = r0 + 8 * j;
    WT[(size_t)(n0 + n) * K + k0 + c] = f2b(t[n][c]);
  }
}

// ---------------------------------------------------------------------------
// RoPE cos/sin table: tab[t*32+idx] = (cos, sin)(pos[t] * 1e6^(-idx/32)).
// Precomputed ONCE; normrope read 40x per (t,idx) previously (redundant
// powf/cosf/sinf on the VALU — Appendix B trig-table guidance).
// ---------------------------------------------------------------------------
__global__ __launch_bounds__(256) void rope_table_kernel(
    const int* __restrict__ positions, float2* __restrict__ tab) {
  const int i = blockIdx.x * 256 + threadIdx.x;  // 0 .. 2048*32-1
  const int t = i >> 5, idx = i & 31;
  const float invf = powf(1.0e6f, -(float)idx * (1.0f / 32.0f));
  const float fr = (float)positions[t] * invf;
  tab[i] = make_float2(cosf(fr), sinf(fr));
}

// ---------------------------------------------------------------------------
// 8-phase BMxBN bf16 MFMA GEMM (r7 schedule — best measured of 7 variants).
// BK=64, 512 thr (8 waves 2Mx4N; per-wave C = BM/2 x BN/4).
// vmcnt ledger: waits leave exactly the next tile's first 2 units in flight
// -> vmcnt(ALOADS+BLOADS). Octet swizzle o ^= (r>>1)&3 on stage-source AND
// ds_read (involution) -> 0 bank conflicts. No XCD swizzle (r11 regression).
// ---------------------------------------------------------------------------
template <int BM, int BN>
__global__ __launch_bounds__(512, 2) void gemm256_kernel(
    const u16* __restrict__ A, const u16* __restrict__ BT,
    float* __restrict__ C, int M, int N, int K) {
  constexpr int WCOLS = BN / 4;
  constexpr int NF = WCOLS / 16;
  constexpr int NF2 = NF / 2;
  constexpr int MF = BM / 32;
  constexpr int ALOADS = BM / 128;
  constexpr int BLOADS = BN / 128;
  constexpr int VMN = ALOADS + BLOADS;
  __shared__ __align__(16) u16 As[2][2][BM * 32];
  __shared__ __align__(16) u16 Bs[2][2][BN * 32];

  const int tid = threadIdx.x;
  const int w = tid >> 6, l = tid & 63;
  const int wr = w >> 2, wc = w & 3;
  const int m = l & 15, g = l >> 4;
  const int bm = blockIdx.y * BM, bn = blockIdx.x * BN;
  const int NT = K >> 6;

  size_t gA[2]; int sA[2];
  size_t gB[2]; int sB[2];
#pragma unroll
  for (int i = 0; i < ALOADS; ++i) {
    const int s = i * 512 + tid;
    const int r = s >> 2, o = s & 3;
    sA[i] = s * 8;
    gA[i] = (size_t)(bm + r) * K + (o ^ ((r >> 1) & 3)) * 8;
  }
#pragma unroll
  for (int i = 0; i < BLOADS; ++i) {
    const int s = i * 512 + tid;
    const int r = s >> 2, o = s & 3;
    sB[i] = s * 8;
    gB[i] = (size_t)(bn + r) * K + (o ^ ((r >> 1) & 3)) * 8;
  }

  const int foff = m * 32 + ((g ^ ((m >> 1) & 3)) * 8);
  const int abase = wr * (BM / 2) * 32;
  const int bbase = wc * WCOLS * 32;

#define STAGE_A(tile, kh)                                                      \
  {                                                                            \
    const size_t kofs = (size_t)(tile) * 64 + (kh) * 32;                       \
    u16* dst = &As[(tile) & 1][kh][0];                                         \
    gll16(A + gA[0] + kofs, dst + sA[0]);                                      \
    if constexpr (ALOADS > 1) gll16(A + gA[1] + kofs, dst + sA[1]);            \
  }
#define STAGE_B(tile, kh)                                                      \
  {                                                                            \
    const size_t kofs = (size_t)(tile) * 64 + (kh) * 32;                       \
    u16* dst = &Bs[(tile) & 1][kh][0];                                         \
    gll16(BT + gB[0] + kofs, dst + sB[0]);                                     \
    if constexpr (BLOADS > 1) gll16(BT + gB[1] + kofs, dst + sB[1]);           \
  }
#define VM_COUNTED()                                                           \
  {                                                                            \
    if constexpr (VMN == 4)                                                    \
      asm volatile("s_waitcnt vmcnt(4)" ::: "memory");                         \
    else                                                                       \
      asm volatile("s_waitcnt vmcnt(3)" ::: "memory");                         \
  }
#define PHASE(j, b, DO_STAGE, tn, VM)                                          \
  {                                                                            \
    constexpr int qn = (j) & 1, kh = (j) >> 1;                                 \
    if constexpr (qn == 0) {                                                   \
      _Pragma("unroll") for (int fm = 0; fm < MF; ++fm)                        \
          af[fm] = *(const bf16x8*)(&As[b][kh][abase + fm * 512 + foff]);      \
    }                                                                          \
    bf16x8 bf[NF2];                                                            \
    _Pragma("unroll") for (int fn = 0; fn < NF2; ++fn)                         \
        bf[fn] =                                                               \
        *(const bf16x8*)(&Bs[b][kh][bbase + (qn * NF2 + fn) * 512 + foff]);    \
    if constexpr (DO_STAGE) {                                                  \
      if constexpr ((j) == 0) STAGE_A(tn, 0);                                  \
      if constexpr ((j) == 1) STAGE_B(tn, 0);                                  \
      if constexpr ((j) == 2) STAGE_A(tn, 1);                                  \
      if constexpr ((j) == 3) STAGE_B(tn, 1);                                  \
    }                                                                          \
    asm volatile("" ::: "memory");                                             \
    __builtin_amdgcn_s_barrier();                                              \
    asm volatile("" ::: "memory");                                             \
    __builtin_amdgcn_s_setprio(1);                                             \
    _Pragma("unroll") for (int fm = 0; fm < MF; ++fm)                          \
        _Pragma("unroll") for (int fn = 0; fn < NF2; ++fn)                     \
        acc[fm][qn * NF2 + fn] = __builtin_amdgcn_mfma_f32_16x16x32_bf16(      \
            af[fm], bf[fn], acc[fm][qn * NF2 + fn], 0, 0, 0);                  \
    __builtin_amdgcn_s_setprio(0);                                             \
    asm volatile("" ::: "memory");                                             \
    if constexpr (((j) & 1) && (VM) == 0)                                      \
      asm volatile("s_waitcnt vmcnt(0)" ::: "memory");                         \
    if constexpr (((j) & 1) && (VM) == 1) VM_COUNTED();                        \
    __builtin_amdgcn_s_barrier();                                              \
    asm volatile("" ::: "memory");                                             \
  }

  f32x4 acc[MF][NF];
#pragma unroll
  for (int i = 0; i < MF; ++i)
#pragma unroll
    for (int j = 0; j < NF; ++j) acc[i][j] = (f32x4){0.f, 0.f, 0.f, 0.f};

  STAGE_A(0, 0); STAGE_B(0, 0); STAGE_A(0, 1); STAGE_B(0, 1);
  VM_COUNTED();
  __builtin_amdgcn_s_barrier();
  asm volatile("" ::: "memory");

  bf16x8 af[MF];
  for (int t = 0; t < NT - 1; ++t) {
    const int b = t & 1, tn = t + 1;
    PHASE(0, b, true, tn, 1);
    PHASE(1, b, true, tn, 1);
    PHASE(2, b, true, tn, 1);
    PHASE(3, b, true, tn, 1);
  }
  {
    const int b = (NT - 1) & 1;
    PHASE(0, b, false, 0, 2);
    PHASE(1, b, false, 0, 0);
    PHASE(2, b, false, 0, 2);
    PHASE(3, b, false, 0, 2);
  }
#undef PHASE
#undef VM_COUNTED
#undef STAGE_B
#undef STAGE_A

#pragma unroll
  for (int fm = 0; fm < MF; ++fm) {
    const int row = bm + wr * (BM / 2) + fm * 16 + g * 4;
#pragma unroll
    for (int fn = 0; fn < NF; ++fn) {
      const int col = bn + wc * WCOLS + fn * 16 + m;
      float* cp = C + (size_t)row * N + col;
#pragma unroll
      for (int r = 0; r < 4; ++r) cp[(size_t)r * N] = acc[fm][fn][r];
    }
  }
}

// ---------------------------------------------------------------------------
// Fused per-head RMSNorm + partial RoPE -> packed bf16 (cos/sin from table).
// ---------------------------------------------------------------------------
__global__ __launch_bounds__(128) void normrope_pack_kernel(
    const float* __restrict__ qkv, const float2* __restrict__ tab,
    const float* __restrict__ qw, const float* __restrict__ kw,
    u16* __restrict__ Qp, u16* __restrict__ Kp) {
  const int t = blockIdx.x;
  const int hh = blockIdx.y;  // 0..39
  const int d = threadIdx.x;  // 0..127
  const bool isq = hh < N_HEADS;
  const int col = isq ? hh * HD : HIDDEN + (hh - N_HEADS) * HD;
  const float* row = qkv + (size_t)t * QKV_N + col;
  const float* w = isq ? qw : kw;

  float x = row[d];
  float ss = x * x;
#pragma unroll
  for (int off = 32; off >= 1; off >>= 1) ss += __shfl_xor(ss, off);
  __shared__ float wsum[2];
  __shared__ float xs[128];
  if ((d & 63) == 0) wsum[d >> 6] = ss;
  __syncthreads();
  const float tot = wsum[0] + wsum[1];
  const float inv = rsqrtf(tot * (1.f / 128.f) + 1e-6f);
  const float xn = x * inv * w[d];
  xs[d] = xn;
  __syncthreads();

  float outv;
  if (d < 64) {
    const int idx = d & 31;
    const float2 cs = tab[t * 32 + idx];
    const float x1 = xs[idx], x2 = xs[idx + 32];
    outv = (d < 32) ? (x1 * cs.x - x2 * cs.y) : (x2 * cs.x + x1 * cs.y);
  } else {
    outv = xn;
  }
  if (isq) {
    Qp[((size_t)hh * T_LEN + t) * HD + d] = f2b(outv * SCALE);
  } else {
    Kp[((size_t)(hh - N_HEADS) * T_LEN + t) * HD + d] = f2b(outv);
  }
}

// ---------------------------------------------------------------------------
// V transpose+cast: qkv V region fp32 [t][d] -> Vtp[kvh][d][t] bf16.
// ---------------------------------------------------------------------------
__global__ __launch_bounds__(256) void vtrans_kernel(
    const float* __restrict__ qkv, u16* __restrict__ Vtp) {
  __shared__ float tile[32][132];
  const int t0 = blockIdx.x * 32;
  const int kvh = blockIdx.y;
  const int tv = threadIdx.x >> 3;          // 0..31
  const int c0 = (threadIdx.x & 7) * 16;    // 0..112
  const float* src =
      qkv + (size_t)(t0 + tv) * QKV_N + (HIDDEN + 1024) + kvh * HD + c0;
#pragma unroll
  for (int u = 0; u < 4; ++u)
    *(f32x4*)&tile[tv][c0 + 4 * u] = *(const f32x4*)(src + 4 * u);
  __syncthreads();
  const int dd = threadIdx.x >> 1;   // 0..127
  const int half = threadIdx.x & 1;  // 0,1
  u16 buf[16];
#pragma unroll
  for (int p = 0; p < 16; ++p) buf[p] = f2b(tile[half * 16 + p][dd]);
  u16* dst = Vtp + ((size_t)kvh * HD + dd) * T_LEN + t0 + half * 16;
  *(uint4*)dst = *(uint4*)&buf[0];
  *(uint4*)(dst + 8) = *(uint4*)&buf[8];
}

// ---------------------------------------------------------------------------
// MFMA causal GQA flash attention (attn4, r8-r13 proven): work-balanced
// pairing + defer-max + setprio. grid (16, 32): block bx handles Q-tiles
// qb = 31-bx then bx (NT sum = 66 const). 256 thr (4 waves), 2 blocks/CU.
// [r14 lesson: bigger Q-tiles (attn5) halved occupancy to 1 wave/SIMD and
// regressed — TLP is what hides the staging latency here.]
// ---------------------------------------------------------------------------
__global__ __launch_bounds__(256, 3) void attn4_kernel(
    const u16* __restrict__ Qp, const u16* __restrict__ Kp,
    const u16* __restrict__ Vtp, u16* __restrict__ outB) {
  __shared__ __align__(16) u16 Qs[64 * 128];
  __shared__ __align__(16) u16 Ks[2 * 32 * 128];
  __shared__ __align__(16) u16 Vts[2 * 128 * 32];
  __shared__ __align__(16) u16 Plds[4 * 16 * 32];

  const int bx = blockIdx.x;  // 0..15
  const int h = blockIdx.y;
  const int kvh = h >> 2;
  const int tid = threadIdx.x;
  const int w = tid >> 6, l = tid & 63;
  const int g = l >> 4, m = l & 15;

  const u16* kbase = Kp + (size_t)kvh * T_LEN * HD;
  const u16* vbase = Vtp + (size_t)kvh * HD * T_LEN;
  u16* pl = Plds + w * 512;  // per-wave P bounce [16 m][32 kv]

#define STAGE_KV(jt, b)                                                        \
  {                                                                            \
    _Pragma("unroll") for (int p = 0; p < 2; ++p) {                            \
      const int krow = p * 16 + w * 4 + (l >> 4);                              \
      const int kg = (l & 15) ^ (krow & 7);                                    \
      gll16(kbase + (size_t)((jt) * 32 + krow) * 128 + kg * 8,                 \
            Ks + (b) * 4096 + p * 2048 + w * 512 + l * 8);                     \
      const int dv = p * 64 + w * 16 + (l >> 2);                               \
      const int vg = (l & 3) ^ ((dv >> 1) & 3);                                \
      gll16(vbase + (size_t)dv * T_LEN + (jt) * 32 + vg * 8,                   \
            Vts + (b) * 4096 + p * 2048 + w * 512 + l * 8);                    \
    }                                                                          \
  }

  for (int job = 0; job < 2; ++job) {
    const int qb = job ? bx : 31 - bx;  // big first (warms KV L2 for small)
    const int t0 = qb * 64;
    const int NT = 2 * (qb + 1);

    // ---- stage Q tile (swizzle: 16B granule ^ (row&7)) ----
    {
      const u16* qbase = Qp + ((size_t)h * T_LEN + t0) * HD;
#pragma unroll
      for (int p = 0; p < 4; ++p) {
        const int row = p * 16 + w * 4 + (l >> 4);
        const int gr = (l & 15) ^ (row & 7);
        gll16(qbase + row * 128 + gr * 8, Qs + p * 2048 + w * 512 + l * 8);
      }
    }
    STAGE_KV(0, 0);
    __syncthreads();

    // ---- hoist Q B-fragments ----
    bf16x8 qf[4];
    {
      const u16* qr = Qs + (w * 16 + m) * 128;
#pragma unroll
      for (int kk = 0; kk < 4; ++kk)
        qf[kk] = *(const bf16x8*)(qr + (((kk * 4 + g) ^ (m & 7)) * 8));
    }

    f32x4 o[8];
#pragma unroll
    for (int n = 0; n < 8; ++n) o[n] = (f32x4){0.f, 0.f, 0.f, 0.f};
    float mrun = -1e30f, lrun = 0.f;

    for (int jt = 0; jt < NT; ++jt) {
      const int b = jt & 1;
      if (jt + 1 < NT) STAGE_KV(jt + 1, b ^ 1);

      // ---- S^T = K @ Q^T ----
      f32x4 s[2];
      s[0] = (f32x4){0.f, 0.f, 0.f, 0.f};
      s[1] = (f32x4){0.f, 0.f, 0.f, 0.f};
      __builtin_amdgcn_s_setprio(1);
#pragma unroll
      for (int f = 0; f < 2; ++f) {
        const u16* kr = Ks + b * 4096 + (f * 16 + m) * 128;
#pragma unroll
        for (int kk = 0; kk < 4; ++kk) {
          bf16x8 kf = *(const bf16x8*)(kr + (((kk * 4 + g) ^ (m & 7)) * 8));
          s[f] =
              __builtin_amdgcn_mfma_f32_16x16x32_bf16(kf, qf[kk], s[f], 0, 0, 0);
        }
      }
      __builtin_amdgcn_s_setprio(0);

      // ---- causal mask (only last two tiles can clip) ----
      if (jt >= NT - 2) {
        const int qg = t0 + w * 16 + m;
        const int kvb = jt * 32 + g * 4;
#pragma unroll
        for (int f = 0; f < 2; ++f)
#pragma unroll
          for (int r = 0; r < 4; ++r)
            if (kvb + f * 16 + r > qg) s[f][r] = -1e30f;
      }

      // ---- online softmax with defer-max (T13, THR=8) ----
      float pm = fmaxf(fmaxf(fmaxf(s[0][0], s[0][1]), fmaxf(s[0][2], s[0][3])),
                       fmaxf(fmaxf(s[1][0], s[1][1]), fmaxf(s[1][2], s[1][3])));
      pm = fmaxf(pm, __shfl_xor(pm, 16));
      pm = fmaxf(pm, __shfl_xor(pm, 32));
      if (!__all(pm <= mrun + 8.f)) {
        const float mn = fmaxf(mrun, pm);
        const float sc = __expf(mrun - mn);
        mrun = mn;
        lrun *= sc;
        f32x4 scr;
#pragma unroll
        for (int r = 0; r < 4; ++r) scr[r] = __shfl(sc, g * 4 + r);
#pragma unroll
        for (int n = 0; n < 8; ++n) o[n] *= scr;
      }
      float ps = 0.f;
#pragma unroll
      for (int f = 0; f < 2; ++f)
#pragma unroll
        for (int r = 0; r < 4; ++r) {
          s[f][r] = __expf(s[f][r] - mrun);
          ps += s[f][r];
        }
      ps += __shfl_xor(ps, 16);
      ps += __shfl_xor(ps, 32);
      lrun += ps;

      // ---- P -> LDS bounce (wave-private) ----
      {
        const u32 a0 = (u32)f2b(s[0][0]) | ((u32)f2b(s[0][1]) << 16);
        const u32 a1 = (u32)f2b(s[0][2]) | ((u32)f2b(s[0][3]) << 16);
        const u32 b0 = (u32)f2b(s[1][0]) | ((u32)f2b(s[1][1]) << 16);
        const u32 b1 = (u32)f2b(s[1][2]) | ((u32)f2b(s[1][3]) << 16);
        *(uint2*)(pl + m * 32 + ((g ^ (m >> 1)) * 4)) = make_uint2(a0, a1);
        *(uint2*)(pl + m * 32 + (((g + 4) ^ (m >> 1)) * 4)) = make_uint2(b0, b1);
      }

      // ---- read P A-fragment ----
      bf16x8 pa;
      {
        const uint2 lo =
            *(const uint2*)(pl + m * 32 + (((2 * g) ^ (m >> 1)) * 4));
        const uint2 hi =
            *(const uint2*)(pl + m * 32 + (((2 * g + 1) ^ (m >> 1)) * 4));
        union { u32 u[4]; bf16x8 v; } pu;
        pu.u[0] = lo.x; pu.u[1] = lo.y; pu.u[2] = hi.x; pu.u[3] = hi.y;
        pa = pu.v;
      }

      // ---- PV ----
      __builtin_amdgcn_s_setprio(1);
#pragma unroll
      for (int n = 0; n < 8; ++n) {
        const int dd = n * 16 + m;
        bf16x8 vf = *(const bf16x8*)(Vts + b * 4096 + dd * 32 +
                                     ((g ^ ((dd >> 1) & 3)) * 8));
        o[n] = __builtin_amdgcn_mfma_f32_16x16x32_bf16(pa, vf, o[n], 0, 0, 0);
      }
      __builtin_amdgcn_s_setprio(0);
      __syncthreads();
    }

    // ---- epilogue: normalize rows, write bf16 [t][h*128+d] ----
    float li[4];
#pragma unroll
    for (int r = 0; r < 4; ++r) li[r] = 1.f / __shfl(lrun, g * 4 + r);
    u16* ob = outB + (size_t)(t0 + w * 16 + g * 4) * HIDDEN + h * HD + m;
#pragma unroll
    for (int n = 0; n < 8; ++n)
#pragma unroll
      for (int r = 0; r < 4; ++r)
        ob[(size_t)r * HIDDEN + n * 16] = f2b(o[n][r] * li[r]);
  }
#undef STAGE_KV
}

// ---------------------------------------------------------------------------
extern "C" void kernel_launch(void* const* d_in, const int* in_sizes, int n_in,
                              void* d_out, int out_size, void* d_ws,
                              size_t ws_size, hipStream_t stream) {
  const float* hidden = (const float*)d_in[0];
  const int* positions = (const int*)d_in[1];
  const float* w_qkv = (const float*)d_in[2];
  const float* w_o = (const float*)d_in[3];
  const float* q_norm_w = (const float*)d_in[4];
  const float* k_norm_w = (const float*)d_in[5];
  float* out = (float*)d_out;

  // workspace layout (~176 MB); Qp aliases hiddenB (dead after GEMM1)
  u16* hiddenB = (u16*)d_ws;                                // 16.8 MB
  u16* Qp = hiddenB;                                        // alias
  u16* wqkvT = hiddenB + (size_t)T_LEN * HIDDEN;            // 50.3 MB
  u16* woT = wqkvT + (size_t)QKV_N * HIDDEN;                // 33.6 MB
  float* qkv = (float*)(woT + (size_t)HIDDEN * HIDDEN);     // 50.3 MB
  u16* attnB = (u16*)(qkv + (size_t)T_LEN * QKV_N);         // 16.8 MB
  u16* Kp = attnB + (size_t)T_LEN * HIDDEN;                 // 4.2 MB
  u16* Vtp = Kp + (size_t)N_KV * T_LEN * HD;                // 4.2 MB
  float2* ropeTab = (float2*)(Vtp + (size_t)N_KV * HD * T_LEN);  // 0.5 MB

  // prep
  cast_bf16_kernel<<<(T_LEN * HIDDEN) / 1024, 256, 0, stream>>>(hidden, hiddenB);
  transpose_cast_kernel<<<dim3(QKV_N / 32, HIDDEN / 32), 256, 0, stream>>>(
      w_qkv, wqkvT, HIDDEN, QKV_N);
  transpose_cast_kernel<<<dim3(HIDDEN / 32, HIDDEN / 32), 256, 0, stream>>>(
      w_o, woT, HIDDEN, HIDDEN);
  rope_table_kernel<<<(T_LEN * 32) / 256, 256, 0, stream>>>(positions, ropeTab);

  // 1) qkv = hidden @ w_qkv  (8-phase 256x256, grid 24x8 = 192)
  gemm256_kernel<256, 256><<<dim3(QKV_N / 256, T_LEN / 256), 512, 0, stream>>>(
      hiddenB, wqkvT, qkv, T_LEN, QKV_N, HIDDEN);
  // 2) RMSNorm + RoPE (table) -> packed bf16 Q/K; V transpose -> Vtp
  normrope_pack_kernel<<<dim3(T_LEN, N_HEADS + N_KV), 128, 0, stream>>>(
      qkv, ropeTab, q_norm_w, k_norm_w, Qp, Kp);
  vtrans_kernel<<<dim3(T_LEN / 32, N_KV), 256, 0, stream>>>(qkv, Vtp);
  // 3) MFMA causal GQA flash attention (balanced pairing) -> bf16
  attn4_kernel<<<dim3(16, N_HEADS), 256, 0, stream>>>(Qp, Kp, Vtp, attnB);
  // 4) out = attn @ w_o  (8-phase 128x256, grid 16x16 = 256 = full coverage)
  gemm256_kernel<128, 256><<<dim3(HIDDEN / 256, T_LEN / 128), 512, 0, stream>>>(
      attnB, woT, out, T_LEN, HIDDEN, HIDDEN);
}

// Round 16
// 349.193 us; speedup vs baseline: 1.1287x; 1.0268x over previous
//
#include <hip/hip_runtime.h>
#include <math.h>

#define HIDDEN 4096
#define QKV_N 6144      // (32 + 2*8) * 128
#define T_LEN 2048
#define HD 128
#define N_HEADS 32
#define N_KV 8
#define SCALE 0.08838834764831845f  // 128^-0.5

typedef unsigned short u16;
typedef unsigned int u32;
typedef __attribute__((ext_vector_type(8))) short bf16x8;
typedef __attribute__((ext_vector_type(4))) float f32x4;

// fp32 -> bf16 round-to-nearest-even
__device__ __forceinline__ u16 f2b(float x) {
  u32 u = __builtin_bit_cast(u32, x);
  u += 0x7fffu + ((u >> 16) & 1u);
  return (u16)(u >> 16);
}

typedef const __attribute__((address_space(1))) void* gas_ptr;
typedef __attribute__((address_space(3))) void* las_ptr;
__device__ __forceinline__ void gll16(const void* g, void* l) {
  __builtin_amdgcn_global_load_lds((gas_ptr)g, (las_ptr)l, 16, 0, 0);
}

// ---------------------------------------------------------------------------
// elementwise fp32 -> bf16 cast (4 elems/thread)
// ---------------------------------------------------------------------------
__global__ __launch_bounds__(256) void cast_bf16_kernel(
    const float* __restrict__ in, u16* __restrict__ out) {
  const size_t i = ((size_t)blockIdx.x * 256 + threadIdx.x) * 4;
  f32x4 v = *(const f32x4*)(in + i);
  ushort4 o;
  o.x = f2b(v[0]); o.y = f2b(v[1]); o.z = f2b(v[2]); o.w = f2b(v[3]);
  *(ushort4*)(out + i) = o;
}

// ---------------------------------------------------------------------------
// W [K][N] fp32 -> WT [N][K] bf16 (32x32 LDS tile transpose) — used for
// w_qkv only; w_o's transpose is absorbed into the attn launch (round 16).
// ---------------------------------------------------------------------------
__global__ __launch_bounds__(256) void transpose_cast_kernel(
    const float* __restrict__ W, u16* __restrict__ WT, int K, int N) {
  __shared__ float t[32][33];
  const int n0 = blockIdx.x * 32, k0 = blockIdx.y * 32;
  const int c = threadIdx.x & 31;
  const int r0 = threadIdx.x >> 5;
#pragma unroll
  for (int j = 0; j < 4; ++j) {
    const int r = r0 + 8 * j;
    t[c][r] = W[(size_t)(k0 + r) * N + n0 + c];
  }
  __syncthreads();
#pragma unroll
  for (int j = 0; j < 4; ++j) {
    const int n = r0 + 8 * j;
    WT[(size_t)(n0 + n) * K + k0 + c] = f2b(t[n][c]);
  }
}

// ---------------------------------------------------------------------------
// 8-phase BMxBN bf16 MFMA GEMM (r7 schedule — best measured of 7 variants).
// BK=64, 512 thr (8 waves 2Mx4N; per-wave C = BM/2 x BN/4).
// vmcnt ledger: waits leave exactly the next tile's first 2 units in flight
// -> vmcnt(ALOADS+BLOADS). Octet swizzle o ^= (r>>1)&3 on stage-source AND
// ds_read (involution) -> 0 bank conflicts. No XCD swizzle (r11 regression).
// ROPE=true (QKV call): gridDim.y = M/BM + 1; the extra by-plane computes
// the RoPE cos/sin table on the 64 CUs the 192-block GEMM leaves idle.
// ---------------------------------------------------------------------------
template <int BM, int BN, bool ROPE>
__global__ __launch_bounds__(512, 2) void gemm256_kernel(
    const u16* __restrict__ A, const u16* __restrict__ BT,
    float* __restrict__ C, int M, int N, int K,
    const int* __restrict__ positions, float2* __restrict__ ropeTab) {
  if constexpr (ROPE) {
    if (blockIdx.y == gridDim.y - 1) {  // rope-table role (24 blocks)
      for (int i = blockIdx.x * 512 + threadIdx.x; i < T_LEN * 32;
           i += gridDim.x * 512) {
        const int t = i >> 5, idx = i & 31;
        const float invf = powf(1.0e6f, -(float)idx * (1.0f / 32.0f));
        const float fr = (float)positions[t] * invf;
        ropeTab[i] = make_float2(cosf(fr), sinf(fr));
      }
      return;
    }
  }
  constexpr int WCOLS = BN / 4;
  constexpr int NF = WCOLS / 16;
  constexpr int NF2 = NF / 2;
  constexpr int MF = BM / 32;
  constexpr int ALOADS = BM / 128;
  constexpr int BLOADS = BN / 128;
  constexpr int VMN = ALOADS + BLOADS;
  __shared__ __align__(16) u16 As[2][2][BM * 32];
  __shared__ __align__(16) u16 Bs[2][2][BN * 32];

  const int tid = threadIdx.x;
  const int w = tid >> 6, l = tid & 63;
  const int wr = w >> 2, wc = w & 3;
  const int m = l & 15, g = l >> 4;
  const int bm = blockIdx.y * BM, bn = blockIdx.x * BN;
  const int NT = K >> 6;

  size_t gA[2]; int sA[2];
  size_t gB[2]; int sB[2];
#pragma unroll
  for (int i = 0; i < ALOADS; ++i) {
    const int s = i * 512 + tid;
    const int r = s >> 2, o = s & 3;
    sA[i] = s * 8;
    gA[i] = (size_t)(bm + r) * K + (o ^ ((r >> 1) & 3)) * 8;
  }
#pragma unroll
  for (int i = 0; i < BLOADS; ++i) {
    const int s = i * 512 + tid;
    const int r = s >> 2, o = s & 3;
    sB[i] = s * 8;
    gB[i] = (size_t)(bn + r) * K + (o ^ ((r >> 1) & 3)) * 8;
  }

  const int foff = m * 32 + ((g ^ ((m >> 1) & 3)) * 8);
  const int abase = wr * (BM / 2) * 32;
  const int bbase = wc * WCOLS * 32;

#define STAGE_A(tile, kh)                                                      \
  {                                                                            \
    const size_t kofs = (size_t)(tile) * 64 + (kh) * 32;                       \
    u16* dst = &As[(tile) & 1][kh][0];                                         \
    gll16(A + gA[0] + kofs, dst + sA[0]);                                      \
    if constexpr (ALOADS > 1) gll16(A + gA[1] + kofs, dst + sA[1]);            \
  }
#define STAGE_B(tile, kh)                                                      \
  {                                                                            \
    const size_t kofs = (size_t)(tile) * 64 + (kh) * 32;                       \
    u16* dst = &Bs[(tile) & 1][kh][0];                                         \
    gll16(BT + gB[0] + kofs, dst + sB[0]);                                     \
    if constexpr (BLOADS > 1) gll16(BT + gB[1] + kofs, dst + sB[1]);           \
  }
#define VM_COUNTED()                                                           \
  {                                                                            \
    if constexpr (VMN == 4)                                                    \
      asm volatile("s_waitcnt vmcnt(4)" ::: "memory");                         \
    else                                                                       \
      asm volatile("s_waitcnt vmcnt(3)" ::: "memory");                         \
  }
#define PHASE(j, b, DO_STAGE, tn, VM)                                          \
  {                                                                            \
    constexpr int qn = (j) & 1, kh = (j) >> 1;                                 \
    if constexpr (qn == 0) {                                                   \
      _Pragma("unroll") for (int fm = 0; fm < MF; ++fm)                        \
          af[fm] = *(const bf16x8*)(&As[b][kh][abase + fm * 512 + foff]);      \
    }                                                                          \
    bf16x8 bf[NF2];                                                            \
    _Pragma("unroll") for (int fn = 0; fn < NF2; ++fn)                         \
        bf[fn] =                                                               \
        *(const bf16x8*)(&Bs[b][kh][bbase + (qn * NF2 + fn) * 512 + foff]);    \
    if constexpr (DO_STAGE) {                                                  \
      if constexpr ((j) == 0) STAGE_A(tn, 0);                                  \
      if constexpr ((j) == 1) STAGE_B(tn, 0);                                  \
      if constexpr ((j) == 2) STAGE_A(tn, 1);                                  \
      if constexpr ((j) == 3) STAGE_B(tn, 1);                                  \
    }                                                                          \
    asm volatile("" ::: "memory");                                             \
    __builtin_amdgcn_s_barrier();                                              \
    asm volatile("" ::: "memory");                                             \
    __builtin_amdgcn_s_setprio(1);                                             \
    _Pragma("unroll") for (int fm = 0; fm < MF; ++fm)                          \
        _Pragma("unroll") for (int fn = 0; fn < NF2; ++fn)                     \
        acc[fm][qn * NF2 + fn] = __builtin_amdgcn_mfma_f32_16x16x32_bf16(      \
            af[fm], bf[fn], acc[fm][qn * NF2 + fn], 0, 0, 0);                  \
    __builtin_amdgcn_s_setprio(0);                                             \
    asm volatile("" ::: "memory");                                             \
    if constexpr (((j) & 1) && (VM) == 0)                                      \
      asm volatile("s_waitcnt vmcnt(0)" ::: "memory");                         \
    if constexpr (((j) & 1) && (VM) == 1) VM_COUNTED();                        \
    __builtin_amdgcn_s_barrier();                                              \
    asm volatile("" ::: "memory");                                             \
  }

  f32x4 acc[MF][NF];
#pragma unroll
  for (int i = 0; i < MF; ++i)
#pragma unroll
    for (int j = 0; j < NF; ++j) acc[i][j] = (f32x4){0.f, 0.f, 0.f, 0.f};

  STAGE_A(0, 0); STAGE_B(0, 0); STAGE_A(0, 1); STAGE_B(0, 1);
  VM_COUNTED();
  __builtin_amdgcn_s_barrier();
  asm volatile("" ::: "memory");

  bf16x8 af[MF];
  for (int t = 0; t < NT - 1; ++t) {
    const int b = t & 1, tn = t + 1;
    PHASE(0, b, true, tn, 1);
    PHASE(1, b, true, tn, 1);
    PHASE(2, b, true, tn, 1);
    PHASE(3, b, true, tn, 1);
  }
  {
    const int b = (NT - 1) & 1;
    PHASE(0, b, false, 0, 2);
    PHASE(1, b, false, 0, 0);
    PHASE(2, b, false, 0, 2);
    PHASE(3, b, false, 0, 2);
  }
#undef PHASE
#undef VM_COUNTED
#undef STAGE_B
#undef STAGE_A

#pragma unroll
  for (int fm = 0; fm < MF; ++fm) {
    const int row = bm + wr * (BM / 2) + fm * 16 + g * 4;
#pragma unroll
    for (int fn = 0; fn < NF; ++fn) {
      const int col = bn + wc * WCOLS + fn * 16 + m;
      float* cp = C + (size_t)row * N + col;
#pragma unroll
      for (int r = 0; r < 4; ++r) cp[(size_t)r * N] = acc[fm][fn][r];
    }
  }
}

// ---------------------------------------------------------------------------
// Fused per-head RMSNorm + partial RoPE -> packed bf16 (cos/sin from table).
// ---------------------------------------------------------------------------
__global__ __launch_bounds__(128) void normrope_pack_kernel(
    const float* __restrict__ qkv, const float2* __restrict__ tab,
    const float* __restrict__ qw, const float* __restrict__ kw,
    u16* __restrict__ Qp, u16* __restrict__ Kp) {
  const int t = blockIdx.x;
  const int hh = blockIdx.y;  // 0..39
  const int d = threadIdx.x;  // 0..127
  const bool isq = hh < N_HEADS;
  const int col = isq ? hh * HD : HIDDEN + (hh - N_HEADS) * HD;
  const float* row = qkv + (size_t)t * QKV_N + col;
  const float* w = isq ? qw : kw;

  float x = row[d];
  float ss = x * x;
#pragma unroll
  for (int off = 32; off >= 1; off >>= 1) ss += __shfl_xor(ss, off);
  __shared__ float wsum[2];
  __shared__ float xs[128];
  if ((d & 63) == 0) wsum[d >> 6] = ss;
  __syncthreads();
  const float tot = wsum[0] + wsum[1];
  const float inv = rsqrtf(tot * (1.f / 128.f) + 1e-6f);
  const float xn = x * inv * w[d];
  xs[d] = xn;
  __syncthreads();

  float outv;
  if (d < 64) {
    const int idx = d & 31;
    const float2 cs = tab[t * 32 + idx];
    const float x1 = xs[idx], x2 = xs[idx + 32];
    outv = (d < 32) ? (x1 * cs.x - x2 * cs.y) : (x2 * cs.x + x1 * cs.y);
  } else {
    outv = xn;
  }
  if (isq) {
    Qp[((size_t)hh * T_LEN + t) * HD + d] = f2b(outv * SCALE);
  } else {
    Kp[((size_t)(hh - N_HEADS) * T_LEN + t) * HD + d] = f2b(outv);
  }
}

// ---------------------------------------------------------------------------
// V transpose+cast: qkv V region fp32 [t][d] -> Vtp[kvh][d][t] bf16.
// ---------------------------------------------------------------------------
__global__ __launch_bounds__(256) void vtrans_kernel(
    const float* __restrict__ qkv, u16* __restrict__ Vtp) {
  __shared__ float tile[32][132];
  const int t0 = blockIdx.x * 32;
  const int kvh = blockIdx.y;
  const int tv = threadIdx.x >> 3;          // 0..31
  const int c0 = (threadIdx.x & 7) * 16;    // 0..112
  const float* src =
      qkv + (size_t)(t0 + tv) * QKV_N + (HIDDEN + 1024) + kvh * HD + c0;
#pragma unroll
  for (int u = 0; u < 4; ++u)
    *(f32x4*)&tile[tv][c0 + 4 * u] = *(const f32x4*)(src + 4 * u);
  __syncthreads();
  const int dd = threadIdx.x >> 1;   // 0..127
  const int half = threadIdx.x & 1;  // 0,1
  u16 buf[16];
#pragma unroll
  for (int p = 0; p < 16; ++p) buf[p] = f2b(tile[half * 16 + p][dd]);
  u16* dst = Vtp + ((size_t)kvh * HD + dd) * T_LEN + t0 + half * 16;
  *(uint4*)dst = *(uint4*)&buf[0];
  *(uint4*)(dst + 8) = *(uint4*)&buf[8];
}

// ---------------------------------------------------------------------------
// MFMA causal GQA flash attention (attn4, r8-r15 proven) + absorbed w_o
// transpose. grid (24, 32): bx<16 = attn (balanced pairing, 2 blocks/CU);
// bx>=16 = 256 transpose blocks x 64 32x32 tiles of w_o (BW-bound work
// hidden under the latency-bound attention; 52KB LDS -> 3 blocks/CU so
// 512 attn + 256 transpose = exactly 3/CU). 256 thr.
// ---------------------------------------------------------------------------
__global__ __launch_bounds__(256, 3) void attn4_kernel(
    const u16* __restrict__ Qp, const u16* __restrict__ Kp,
    const u16* __restrict__ Vtp, u16* __restrict__ outB,
    const float* __restrict__ w_o, u16* __restrict__ woT) {
  __shared__ __align__(16) u16 Qs[64 * 128];
  __shared__ __align__(16) u16 Ks[2 * 32 * 128];
  __shared__ __align__(16) u16 Vts[2 * 128 * 32];
  __shared__ __align__(16) u16 Plds[4 * 16 * 32];

  const int bx = blockIdx.x;  // 0..23
  const int h = blockIdx.y;
  const int tid = threadIdx.x;

  if (bx >= 16) {  // ---- w_o transpose role (256 blocks x 64 tiles) ----
    float(*tf)[33] = (float(*)[33])Qs;  // 4.2KB alias into Qs
    const int e = (bx - 16) + 8 * h;    // 0..255
    const int c = tid & 31, rr = tid >> 5;
    for (int tt = e * 64; tt < e * 64 + 64; ++tt) {
      const int n0 = (tt & 127) * 32, k0 = (tt >> 7) * 32;
#pragma unroll
      for (int j = 0; j < 4; ++j) {
        const int r = rr + 8 * j;
        tf[c][r] = w_o[(size_t)(k0 + r) * HIDDEN + n0 + c];
      }
      __syncthreads();
#pragma unroll
      for (int j = 0; j < 4; ++j) {
        const int n = rr + 8 * j;
        woT[(size_t)(n0 + n) * HIDDEN + k0 + c] = f2b(tf[n][c]);
      }
      __syncthreads();
    }
    return;
  }

  const int kvh = h >> 2;
  const int w = tid >> 6, l = tid & 63;
  const int g = l >> 4, m = l & 15;

  const u16* kbase = Kp + (size_t)kvh * T_LEN * HD;
  const u16* vbase = Vtp + (size_t)kvh * HD * T_LEN;
  u16* pl = Plds + w * 512;  // per-wave P bounce [16 m][32 kv]

#define STAGE_KV(jt, b)                                                        \
  {                                                                            \
    _Pragma("unroll") for (int p = 0; p < 2; ++p) {                            \
      const int krow = p * 16 + w * 4 + (l >> 4);                              \
      const int kg = (l & 15) ^ (krow & 7);                                    \
      gll16(kbase + (size_t)((jt) * 32 + krow) * 128 + kg * 8,                 \
            Ks + (b) * 4096 + p * 2048 + w * 512 + l * 8);                     \
      const int dv = p * 64 + w * 16 + (l >> 2);                               \
      const int vg = (l & 3) ^ ((dv >> 1) & 3);                                \
      gll16(vbase + (size_t)dv * T_LEN + (jt) * 32 + vg * 8,                   \
            Vts + (b) * 4096 + p * 2048 + w * 512 + l * 8);                    \
    }                                                                          \
  }

  for (int job = 0; job < 2; ++job) {
    const int qb = job ? bx : 31 - bx;  // big first (warms KV L2 for small)
    const int t0 = qb * 64;
    const int NT = 2 * (qb + 1);

    // ---- stage Q tile (swizzle: 16B granule ^ (row&7)) ----
    {
      const u16* qbase = Qp + ((size_t)h * T_LEN + t0) * HD;
#pragma unroll
      for (int p = 0; p < 4; ++p) {
        const int row = p * 16 + w * 4 + (l >> 4);
        const int gr = (l & 15) ^ (row & 7);
        gll16(qbase + row * 128 + gr * 8, Qs + p * 2048 + w * 512 + l * 8);
      }
    }
    STAGE_KV(0, 0);
    __syncthreads();

    // ---- hoist Q B-fragments ----
    bf16x8 qf[4];
    {
      const u16* qr = Qs + (w * 16 + m) * 128;
#pragma unroll
      for (int kk = 0; kk < 4; ++kk)
        qf[kk] = *(const bf16x8*)(qr + (((kk * 4 + g) ^ (m & 7)) * 8));
    }

    f32x4 o[8];
#pragma unroll
    for (int n = 0; n < 8; ++n) o[n] = (f32x4){0.f, 0.f, 0.f, 0.f};
    float mrun = -1e30f, lrun = 0.f;

    for (int jt = 0; jt < NT; ++jt) {
      const int b = jt & 1;
      if (jt + 1 < NT) STAGE_KV(jt + 1, b ^ 1);

      // ---- S^T = K @ Q^T ----
      f32x4 s[2];
      s[0] = (f32x4){0.f, 0.f, 0.f, 0.f};
      s[1] = (f32x4){0.f, 0.f, 0.f, 0.f};
      __builtin_amdgcn_s_setprio(1);
#pragma unroll
      for (int f = 0; f < 2; ++f) {
        const u16* kr = Ks + b * 4096 + (f * 16 + m) * 128;
#pragma unroll
        for (int kk = 0; kk < 4; ++kk) {
          bf16x8 kf = *(const bf16x8*)(kr + (((kk * 4 + g) ^ (m & 7)) * 8));
          s[f] =
              __builtin_amdgcn_mfma_f32_16x16x32_bf16(kf, qf[kk], s[f], 0, 0, 0);
        }
      }
      __builtin_amdgcn_s_setprio(0);

      // ---- causal mask (only last two tiles can clip) ----
      if (jt >= NT - 2) {
        const int qg = t0 + w * 16 + m;
        const int kvb = jt * 32 + g * 4;
#pragma unroll
        for (int f = 0; f < 2; ++f)
#pragma unroll
          for (int r = 0; r < 4; ++r)
            if (kvb + f * 16 + r > qg) s[f][r] = -1e30f;
      }

      // ---- online softmax with defer-max (T13, THR=8) ----
      float pm = fmaxf(fmaxf(fmaxf(s[0][0], s[0][1]), fmaxf(s[0][2], s[0][3])),
                       fmaxf(fmaxf(s[1][0], s[1][1]), fmaxf(s[1][2], s[1][3])));
      pm = fmaxf(pm, __shfl_xor(pm, 16));
      pm = fmaxf(pm, __shfl_xor(pm, 32));
      if (!__all(pm <= mrun + 8.f)) {
        const float mn = fmaxf(mrun, pm);
        const float sc = __expf(mrun - mn);
        mrun = mn;
        lrun *= sc;
        f32x4 scr;
#pragma unroll
        for (int r = 0; r < 4; ++r) scr[r] = __shfl(sc, g * 4 + r);
#pragma unroll
        for (int n = 0; n < 8; ++n) o[n] *= scr;
      }
      float ps = 0.f;
#pragma unroll
      for (int f = 0; f < 2; ++f)
#pragma unroll
        for (int r = 0; r < 4; ++r) {
          s[f][r] = __expf(s[f][r] - mrun);
          ps += s[f][r];
        }
      ps += __shfl_xor(ps, 16);
      ps += __shfl_xor(ps, 32);
      lrun += ps;

      // ---- P -> LDS bounce (wave-private) ----
      {
        const u32 a0 = (u32)f2b(s[0][0]) | ((u32)f2b(s[0][1]) << 16);
        const u32 a1 = (u32)f2b(s[0][2]) | ((u32)f2b(s[0][3]) << 16);
        const u32 b0 = (u32)f2b(s[1][0]) | ((u32)f2b(s[1][1]) << 16);
        const u32 b1 = (u32)f2b(s[1][2]) | ((u32)f2b(s[1][3]) << 16);
        *(uint2*)(pl + m * 32 + ((g ^ (m >> 1)) * 4)) = make_uint2(a0, a1);
        *(uint2*)(pl + m * 32 + (((g + 4) ^ (m >> 1)) * 4)) = make_uint2(b0, b1);
      }

      // ---- read P A-fragment ----
      bf16x8 pa;
      {
        const uint2 lo =
            *(const uint2*)(pl + m * 32 + (((2 * g) ^ (m >> 1)) * 4));
        const uint2 hi =
            *(const uint2*)(pl + m * 32 + (((2 * g + 1) ^ (m >> 1)) * 4));
        union { u32 u[4]; bf16x8 v; } pu;
        pu.u[0] = lo.x; pu.u[1] = lo.y; pu.u[2] = hi.x; pu.u[3] = hi.y;
        pa = pu.v;
      }

      // ---- PV ----
      __builtin_amdgcn_s_setprio(1);
#pragma unroll
      for (int n = 0; n < 8; ++n) {
        const int dd = n * 16 + m;
        bf16x8 vf = *(const bf16x8*)(Vts + b * 4096 + dd * 32 +
                                     ((g ^ ((dd >> 1) & 3)) * 8));
        o[n] = __builtin_amdgcn_mfma_f32_16x16x32_bf16(pa, vf, o[n], 0, 0, 0);
      }
      __builtin_amdgcn_s_setprio(0);
      __syncthreads();
    }

    // ---- epilogue: normalize rows, write bf16 [t][h*128+d] ----
    float li[4];
#pragma unroll
    for (int r = 0; r < 4; ++r) li[r] = 1.f / __shfl(lrun, g * 4 + r);
    u16* ob = outB + (size_t)(t0 + w * 16 + g * 4) * HIDDEN + h * HD + m;
#pragma unroll
    for (int n = 0; n < 8; ++n)
#pragma unroll
      for (int r = 0; r < 4; ++r)
        ob[(size_t)r * HIDDEN + n * 16] = f2b(o[n][r] * li[r]);
  }
#undef STAGE_KV
}

// ---------------------------------------------------------------------------
extern "C" void kernel_launch(void* const* d_in, const int* in_sizes, int n_in,
                              void* d_out, int out_size, void* d_ws,
                              size_t ws_size, hipStream_t stream) {
  const float* hidden = (const float*)d_in[0];
  const int* positions = (const int*)d_in[1];
  const float* w_qkv = (const float*)d_in[2];
  const float* w_o = (const float*)d_in[3];
  const float* q_norm_w = (const float*)d_in[4];
  const float* k_norm_w = (const float*)d_in[5];
  float* out = (float*)d_out;

  // workspace layout (~176 MB); Qp aliases hiddenB (dead after GEMM1)
  u16* hiddenB = (u16*)d_ws;                                // 16.8 MB
  u16* Qp = hiddenB;                                        // alias
  u16* wqkvT = hiddenB + (size_t)T_LEN * HIDDEN;            // 50.3 MB
  u16* woT = wqkvT + (size_t)QKV_N * HIDDEN;                // 33.6 MB
  float* qkv = (float*)(woT + (size_t)HIDDEN * HIDDEN);     // 50.3 MB
  u16* attnB = (u16*)(qkv + (size_t)T_LEN * QKV_N);         // 16.8 MB
  u16* Kp = attnB + (size_t)T_LEN * HIDDEN;                 // 4.2 MB
  u16* Vtp = Kp + (size_t)N_KV * T_LEN * HD;                // 4.2 MB
  float2* ropeTab = (float2*)(Vtp + (size_t)N_KV * HD * T_LEN);  // 0.5 MB

  // prep (w_o transpose and rope table are absorbed into later launches)
  cast_bf16_kernel<<<(T_LEN * HIDDEN) / 1024, 256, 0, stream>>>(hidden, hiddenB);
  transpose_cast_kernel<<<dim3(QKV_N / 32, HIDDEN / 32), 256, 0, stream>>>(
      w_qkv, wqkvT, HIDDEN, QKV_N);

  // 1) qkv = hidden @ w_qkv  (8-phase 256x256, grid 24x(8+1): +rope plane)
  gemm256_kernel<256, 256, true>
      <<<dim3(QKV_N / 256, T_LEN / 256 + 1), 512, 0, stream>>>(
          hiddenB, wqkvT, qkv, T_LEN, QKV_N, HIDDEN, positions, ropeTab);
  // 2) RMSNorm + RoPE (table) -> packed bf16 Q/K; V transpose -> Vtp
  normrope_pack_kernel<<<dim3(T_LEN, N_HEADS + N_KV), 128, 0, stream>>>(
      qkv, ropeTab, q_norm_w, k_norm_w, Qp, Kp);
  vtrans_kernel<<<dim3(T_LEN / 32, N_KV), 256, 0, stream>>>(qkv, Vtp);
  // 3) attn (bx<16) + absorbed w_o transpose (bx>=16) -> attnB, woT
  attn4_kernel<<<dim3(24, N_HEADS), 256, 0, stream>>>(Qp, Kp, Vtp, attnB, w_o,
                                                      woT);
  // 4) out = attn @ w_o  (8-phase 128x256, grid 16x16 = 256 = full coverage)
  gemm256_kernel<128, 256, false>
      <<<dim3(HIDDEN / 256, T_LEN / 128), 512, 0, stream>>>(
          attnB, woT, out, T_LEN, HIDDEN, HIDDEN, nullptr, nullptr);
}